// Round 1
// baseline (91037.433 us; speedup 1.0000x reference)
//
#include <hip/hip_runtime.h>
#include <stdint.h>
#include <math.h>

typedef __attribute__((ext_vector_type(8))) short bf16x8;
typedef __attribute__((ext_vector_type(4))) float f32x4;

#define BATCH 4
#define T_M 32
#define DE 128
#define T_W 2560
#define DXW 512
#define DHW 896
#define NROW 2688
#define NG 224        /* wav-rnn workgroups; 896/224 = 4 units per WG */
#define RPW 12        /* gate rows per WG = 3 gates * 4 units */
#define WPAD 1416     /* padded K (512+896+8): stride 2832B -> bank offset 4, 16B aligned */

__device__ __forceinline__ float b2f(unsigned short h) {
  return __uint_as_float(((unsigned int)h) << 16);
}
__device__ __forceinline__ unsigned short f2b(float f) {
  unsigned int u = __float_as_uint(f);
  u = u + 0x7fffu + ((u >> 16) & 1u);   // RNE
  return (unsigned short)(u >> 16);
}
__device__ __forceinline__ float blo(unsigned int u){ return __uint_as_float(u << 16); }
__device__ __forceinline__ float bhi(unsigned int u){ return __uint_as_float(u & 0xffff0000u); }
__device__ __forceinline__ float sigm(float x){ return 1.f / (1.f + __expf(-x)); }
__device__ __forceinline__ float gelu_exact(float x){ return 0.5f * x * (1.f + erff(x * 0.70710678118654752f)); }

// ---------------- encoder: input projections gi = in @ Wih^T + bih ----------------
// grid = 128 (t*4+b), block = 384 (one row per thread)
__global__ __launch_bounds__(384) void k_gi_enc(
    const float* __restrict__ in, const float* __restrict__ Wih,
    const float* __restrict__ bih, float* __restrict__ out, int K)
{
  __shared__ float in_s[256];
  int tb = blockIdx.x;
  for (int i = threadIdx.x; i < K; i += 384) in_s[i] = in[tb * K + i];
  __syncthreads();
  int row = threadIdx.x;
  float acc = bih[row];
  const float* wr = Wih + row * K;
  for (int k = 0; k < K; ++k) acc += in_s[k] * wr[k];
  out[tb * 384 + row] = acc;
}

// ---------------- encoder: sequential scan, one WG per direction ----------------
// grid = 2 (0=fwd,1=bwd), block = 512. Whh read from global (L1/L2 cached), h in LDS (bf16).
__global__ __launch_bounds__(512) void k_scan_enc(
    const float* __restrict__ gi_f, const float* __restrict__ gi_b,
    const float* __restrict__ whh_f, const float* __restrict__ bhh_f,
    const float* __restrict__ whh_b, const float* __restrict__ bhh_b,
    float* __restrict__ c_out)   // (32,4,256)
{
  const int dir = blockIdx.x, tid = threadIdx.x;
  const float* gi  = dir ? gi_b  : gi_f;
  const float* whh = dir ? whh_b : whh_f;
  const float* bhh = dir ? bhh_b : bhh_f;
  __shared__ unsigned short h_s[BATCH][DE + 8];
  __shared__ float gh_s[384][4];
  __shared__ float bhh_s[384];
  for (int i = tid; i < 384; i += 512) bhh_s[i] = bhh[i];
  for (int i = tid; i < BATCH * (DE + 8); i += 512) ((unsigned short*)h_s)[i] = 0;
  __syncthreads();
  for (int s = 0; s < T_M; ++s) {
    int t = dir ? (T_M - 1 - s) : s;
    #pragma unroll
    for (int k3 = 0; k3 < 3; ++k3) {
      int d = tid + 512 * k3;            // 1536 dots: row = d>>2, b = d&3
      int row = d >> 2, b = d & 3;
      const float* wr = whh + row * DE;
      float acc = 0.f;
      for (int j = 0; j < DE; j += 8) {
        float4 w0 = *(const float4*)(wr + j);
        float4 w1 = *(const float4*)(wr + j + 4);
        uint4  hv = *(const uint4*)&h_s[b][j];
        acc += w0.x * blo(hv.x) + w0.y * bhi(hv.x) + w0.z * blo(hv.y) + w0.w * bhi(hv.y);
        acc += w1.x * blo(hv.z) + w1.y * bhi(hv.z) + w1.z * blo(hv.w) + w1.w * bhi(hv.w);
      }
      gh_s[row][b] = acc + bhh_s[row];
    }
    __syncthreads();
    {
      int u = tid >> 2, b = tid & 3;     // 512 = 128 units * 4 batch
      const float* git = gi + (t * BATCH + b) * 384;
      float r = sigm(git[u] + gh_s[u][b]);
      float z = sigm(git[DE + u] + gh_s[DE + u][b]);
      float n = tanhf(git[2 * DE + u] + r * gh_s[2 * DE + u][b]);
      float hold = b2f(h_s[b][u]);
      float hnew = (1.f - z) * n + z * hold;
      c_out[(t * BATCH + b) * 256 + dir * DE + u] = hnew;
      h_s[b][u] = f2b(hnew);
    }
    __syncthreads();
  }
}

// ---------------- build wav-GRU input X = [embed(quantize(shifted y)), upsampled c] in bf16 ----
// grid = 2560, block = 256
__global__ __launch_bounds__(256) void k_build_X(
    const float* __restrict__ y, const float* __restrict__ E,
    const float* __restrict__ c1, unsigned short* __restrict__ X)
{
  int t = blockIdx.x, c = threadIdx.x;
  int tm = t / 80;
  #pragma unroll
  for (int b = 0; b < BATCH; ++b) {
    float w = (t == 0) ? 0.f : y[(t - 1) * BATCH + b];
    int q = (int)floorf((w + 1.f) * 128.f);
    q = q < 0 ? 0 : (q > 255 ? 255 : q);
    unsigned short* xb = X + (size_t)(t * BATCH + b) * DXW;
    xb[c]       = f2b(E[q * 256 + c]);
    xb[256 + c] = f2b(c1[(tm * BATCH + b) * 256 + c]);
  }
}

// ---------------- wav GRU: persistent cooperative kernel, 224 WGs, MFMA dots ----------------
__global__ __launch_bounds__(256, 1) void k_wav_rnn(
    const float* __restrict__ wih,   // (2688,512)
    const float* __restrict__ whh,   // (2688,896)
    const float* __restrict__ bih, const float* __restrict__ bhh,
    const unsigned short* __restrict__ X,     // (2560,4,512) bf16
    unsigned short* __restrict__ hbuf,        // (2,4,896) bf16, zeroed
    unsigned short* __restrict__ O,           // (2560,4,896) bf16
    int* __restrict__ flags,                  // 224 * 16 ints (64B lines), zeroed
    int* __restrict__ gstep)                  // zeroed
{
  const int wg = blockIdx.x, tid = threadIdx.x;
  const int lane = tid & 63, wave = tid >> 6;

  __shared__ unsigned short wcat_s[RPW][WPAD];   // [row][0:512 wih | 512:1408 whh]
  __shared__ unsigned short xh_s[BATCH][WPAD];   // [b][0:512 x_t | 512:1408 h_t]
  __shared__ float pih_s[4][16][4];              // [wave][row][b]
  __shared__ float phh_s[4][16][4];
  __shared__ float bih_s[RPW], bhh_s[RPW];

  // preload weight slice (rows r = g*4+u -> global row g*896 + wg*4 + u), bf16
  for (int idx = tid; idx < RPW * 512; idx += 256) {
    int r = idx >> 9, c = idx & 511;
    int g = r >> 2, u = r & 3;
    wcat_s[r][c] = f2b(wih[(size_t)(g * 896 + wg * 4 + u) * 512 + c]);
  }
  for (int idx = tid; idx < RPW * 896; idx += 256) {
    int r = idx / 896, c = idx - r * 896;
    int g = r >> 2, u = r & 3;
    wcat_s[r][512 + c] = f2b(whh[(size_t)(g * 896 + wg * 4 + u) * 896 + c]);
  }
  if (tid < RPW) {
    int g = tid >> 2, u = tid & 3;
    bih_s[tid] = bih[g * 896 + wg * 4 + u];
    bhh_s[tid] = bhh[g * 896 + wg * 4 + u];
  }
  __syncthreads();

  const int mrow = (lane & 15) < RPW ? (lane & 15) : (RPW - 1);  // A row (clamped dup)
  const int bcol = (lane & 15) & 3;                              // B col wrapped to batch
  const int quad = lane >> 4;

  for (int t = 0; t < T_W; ++t) {
    // stage x_t and h_t into LDS (uint copies)
    {
      const unsigned int* xt = (const unsigned int*)(X + (size_t)t * 2048);
      for (int i = tid; i < 1024; i += 256) {
        int b = i >> 8, c = i & 255;
        ((unsigned int*)&xh_s[b][0])[c] = xt[i];
      }
      const unsigned int* hsrc = (const unsigned int*)(hbuf + (t & 1) * 3584);
      for (int i = tid; i < 1792; i += 256) {
        int b = i / 448, c = i - b * 448;
        ((unsigned int*)&xh_s[b][512])[c] = hsrc[i];
      }
    }
    __syncthreads();

    // MFMA: D[m=row][n=batch] = sum_k W[row][k] * xh[b][k]; separate ih / hh accumulators
    f32x4 aih = {0.f, 0.f, 0.f, 0.f};
    f32x4 ahh = {0.f, 0.f, 0.f, 0.f};
    #pragma unroll
    for (int kc = 0; kc < 4; ++kc) {            // ih: 16 chunks of 32 across 4 waves
      int k0 = (wave * 4 + kc) * 32;
      bf16x8 a = *(const bf16x8*)&wcat_s[mrow][k0 + quad * 8];
      bf16x8 b = *(const bf16x8*)&xh_s[bcol][k0 + quad * 8];
      aih = __builtin_amdgcn_mfma_f32_16x16x32_bf16(a, b, aih, 0, 0, 0);
    }
    #pragma unroll
    for (int kc = 0; kc < 7; ++kc) {            // hh: 28 chunks across 4 waves
      int k0 = 512 + (wave * 7 + kc) * 32;
      bf16x8 a = *(const bf16x8*)&wcat_s[mrow][k0 + quad * 8];
      bf16x8 b = *(const bf16x8*)&xh_s[bcol][k0 + quad * 8];
      ahh = __builtin_amdgcn_mfma_f32_16x16x32_bf16(a, b, ahh, 0, 0, 0);
    }
    if ((lane & 15) < 4) {   // C/D layout: col = lane&15, row = quad*4 + reg
      #pragma unroll
      for (int r = 0; r < 4; ++r) {
        pih_s[wave][quad * 4 + r][bcol] = aih[r];
        phh_s[wave][quad * 4 + r][bcol] = ahh[r];
      }
    }
    __syncthreads();

    // finalize 16 h values (4 units * 4 batch)
    if (tid < 16) {
      int u = tid >> 2, b = tid & 3;
      float ihr = 0.f, hhr = 0.f, ihz = 0.f, hhz = 0.f, ihn = 0.f, hhn = 0.f;
      #pragma unroll
      for (int w = 0; w < 4; ++w) {
        ihr += pih_s[w][u][b];      hhr += phh_s[w][u][b];
        ihz += pih_s[w][4 + u][b];  hhz += phh_s[w][4 + u][b];
        ihn += pih_s[w][8 + u][b];  hhn += phh_s[w][8 + u][b];
      }
      ihr += bih_s[u];     hhr += bhh_s[u];
      ihz += bih_s[4 + u]; hhz += bhh_s[4 + u];
      ihn += bih_s[8 + u]; hhn += bhh_s[8 + u];
      float r = sigm(ihr + hhr);
      float z = sigm(ihz + hhz);
      float n = tanhf(ihn + r * hhn);
      float hold = b2f(xh_s[b][512 + wg * 4 + u]);
      float hnew = (1.f - z) * n + z * hold;
      unsigned short hb = f2b(hnew);
      hbuf[((t + 1) & 1) * 3584 + b * 896 + wg * 4 + u] = hb;
      O[(size_t)(t * 4 + b) * 896 + wg * 4 + u] = hb;
    }
    __threadfence();     // flush h stores to device scope
    __syncthreads();
    if (tid == 0)
      __hip_atomic_store(&flags[wg * 16], t + 1, __ATOMIC_RELEASE, __HIP_MEMORY_SCOPE_AGENT);

    if (wg == 0) {       // master gathers arrivals, publishes step
      if (tid < NG) {
        while (__hip_atomic_load(&flags[tid * 16], __ATOMIC_RELAXED, __HIP_MEMORY_SCOPE_AGENT) < t + 1)
          __builtin_amdgcn_s_sleep(1);
      }
      __syncthreads();
      if (tid == 0)
        __hip_atomic_store(gstep, t + 1, __ATOMIC_RELEASE, __HIP_MEMORY_SCOPE_AGENT);
    }
    if (tid == 0) {
      while (__hip_atomic_load(gstep, __ATOMIC_RELAXED, __HIP_MEMORY_SCOPE_AGENT) < t + 1)
        __builtin_amdgcn_s_sleep(1);
    }
    __syncthreads();
    __threadfence();     // invalidate caches before reading new h next iteration
  }
}

// ---------------- head GEMM: C = act(A(bf16, MxK) @ Bw(f32, NxK)^T + bias) ----------------
// grid = (M/64, N/64), block = 256, 4x4 micro-tile
__global__ __launch_bounds__(256) void k_gemm(
    const unsigned short* __restrict__ A, const float* __restrict__ Bw,
    const float* __restrict__ bias, void* __restrict__ Cout,
    int M, int N, int K, int act, int c_bf16)
{
  const int m0 = blockIdx.x * 64, n0 = blockIdx.y * 64;
  const int tid = threadIdx.x;
  __shared__ float As[32][68];
  __shared__ float Bs[32][68];
  const int ty = tid >> 4, tx = tid & 15;
  const int ml = tid >> 2, kg = tid & 3;
  float acc[4][4] = {{0.f}};
  for (int kt = 0; kt < K; kt += 32) {
    uint4 av = *(const uint4*)(A + (size_t)(m0 + ml) * K + kt + kg * 8);
    const float* bp = Bw + (size_t)(n0 + ml) * K + kt + kg * 8;
    float4 b0 = *(const float4*)bp;
    float4 b1 = *(const float4*)(bp + 4);
    As[kg * 8 + 0][ml] = blo(av.x); As[kg * 8 + 1][ml] = bhi(av.x);
    As[kg * 8 + 2][ml] = blo(av.y); As[kg * 8 + 3][ml] = bhi(av.y);
    As[kg * 8 + 4][ml] = blo(av.z); As[kg * 8 + 5][ml] = bhi(av.z);
    As[kg * 8 + 6][ml] = blo(av.w); As[kg * 8 + 7][ml] = bhi(av.w);
    Bs[kg * 8 + 0][ml] = b0.x; Bs[kg * 8 + 1][ml] = b0.y;
    Bs[kg * 8 + 2][ml] = b0.z; Bs[kg * 8 + 3][ml] = b0.w;
    Bs[kg * 8 + 4][ml] = b1.x; Bs[kg * 8 + 5][ml] = b1.y;
    Bs[kg * 8 + 6][ml] = b1.z; Bs[kg * 8 + 7][ml] = b1.w;
    __syncthreads();
    #pragma unroll
    for (int k = 0; k < 32; ++k) {
      float4 a4 = *(const float4*)&As[k][ty * 4];
      float4 b4 = *(const float4*)&Bs[k][tx * 4];
      acc[0][0] += a4.x * b4.x; acc[0][1] += a4.x * b4.y; acc[0][2] += a4.x * b4.z; acc[0][3] += a4.x * b4.w;
      acc[1][0] += a4.y * b4.x; acc[1][1] += a4.y * b4.y; acc[1][2] += a4.y * b4.z; acc[1][3] += a4.y * b4.w;
      acc[2][0] += a4.z * b4.x; acc[2][1] += a4.z * b4.y; acc[2][2] += a4.z * b4.z; acc[2][3] += a4.z * b4.w;
      acc[3][0] += a4.w * b4.x; acc[3][1] += a4.w * b4.y; acc[3][2] += a4.w * b4.z; acc[3][3] += a4.w * b4.w;
    }
    __syncthreads();
  }
  #pragma unroll
  for (int i = 0; i < 4; ++i) {
    int mi = m0 + ty * 4 + i;
    #pragma unroll
    for (int j = 0; j < 4; ++j) {
      int nj = n0 + tx * 4 + j;
      float v = acc[i][j] + bias[nj];
      if (act) v = gelu_exact(v);
      if (c_bf16) ((unsigned short*)Cout)[(size_t)mi * N + nj] = f2b(v);
      else        ((float*)Cout)[(size_t)mi * N + nj] = v;
    }
  }
}

// ---------------- NLL: per-row logsumexp + target gather, atomic accumulate ----------------
// grid = 2560, block = 256 (one row per wave)
__global__ __launch_bounds__(256) void k_nll(
    const float* __restrict__ logits, const float* __restrict__ y,
    float* __restrict__ acc)
{
  int wid = threadIdx.x >> 6, lane = threadIdx.x & 63;
  int row = blockIdx.x * 4 + wid;
  const float* lr = logits + (size_t)row * 256;
  float v0 = lr[lane], v1 = lr[lane + 64], v2 = lr[lane + 128], v3 = lr[lane + 192];
  float mx = fmaxf(fmaxf(v0, v1), fmaxf(v2, v3));
  for (int off = 32; off > 0; off >>= 1) mx = fmaxf(mx, __shfl_xor(mx, off));
  float se = __expf(v0 - mx) + __expf(v1 - mx) + __expf(v2 - mx) + __expf(v3 - mx);
  for (int off = 32; off > 0; off >>= 1) se += __shfl_xor(se, off);
  if (lane == 0) {
    float w = y[row];
    int q = (int)floorf((w + 1.f) * 128.f);
    q = q < 0 ? 0 : (q > 255 ? 255 : q);
    float contrib = (logf(se) + mx) - lr[q];
    atomicAdd(acc, contrib);
  }
}

__global__ void k_final(const float* __restrict__ acc, float* __restrict__ out) {
  out[0] = acc[0] * (1.f / 10240.f);
}

// ---------------- host ----------------
extern "C" void kernel_launch(void* const* d_in, const int* in_sizes, int n_in,
                              void* d_out, int out_size, void* d_ws, size_t ws_size,
                              hipStream_t stream)
{
  const float* x       = (const float*)d_in[0];
  const float* y       = (const float*)d_in[1];
  const float* m0f_Wih = (const float*)d_in[2];
  const float* m0f_Whh = (const float*)d_in[3];
  const float* m0f_bih = (const float*)d_in[4];
  const float* m0f_bhh = (const float*)d_in[5];
  const float* m0b_Wih = (const float*)d_in[6];
  const float* m0b_Whh = (const float*)d_in[7];
  const float* m0b_bih = (const float*)d_in[8];
  const float* m0b_bhh = (const float*)d_in[9];
  const float* m1f_Wih = (const float*)d_in[10];
  const float* m1f_Whh = (const float*)d_in[11];
  const float* m1f_bih = (const float*)d_in[12];
  const float* m1f_bhh = (const float*)d_in[13];
  const float* m1b_Wih = (const float*)d_in[14];
  const float* m1b_Whh = (const float*)d_in[15];
  const float* m1b_bih = (const float*)d_in[16];
  const float* m1b_bhh = (const float*)d_in[17];
  const float* w_Wih   = (const float*)d_in[18];
  const float* w_Whh   = (const float*)d_in[19];
  const float* w_bih   = (const float*)d_in[20];
  const float* w_bhh   = (const float*)d_in[21];
  const float* Wp      = (const float*)d_in[22];
  const float* bp      = (const float*)d_in[23];
  const float* E       = (const float*)d_in[24];
  const float* Wd      = (const float*)d_in[25];
  const float* bd      = (const float*)d_in[26];

  char* ws = (char*)d_ws;
  size_t off = 0;
  auto alloc = [&](size_t bytes) -> void* {
    void* p = ws + off;
    off += (bytes + 255) & ~(size_t)255;
    return p;
  };
  // misc region (zeroed every launch): flags, gstep, nll acc, h double-buffer
  int*            flags = (int*)alloc(NG * 16 * sizeof(int));
  int*            gstep = (int*)alloc(64);
  float*          nacc  = (float*)alloc(64);
  unsigned short* hbuf  = (unsigned short*)alloc(2 * 4 * 896 * sizeof(unsigned short));
  size_t misc_bytes = off;

  float* c0   = (float*)alloc((size_t)32 * 4 * 256 * 4);
  float* c1   = (float*)alloc((size_t)32 * 4 * 256 * 4);
  float* gi0f = (float*)alloc((size_t)32 * 4 * 384 * 4);
  float* gi0b = (float*)alloc((size_t)32 * 4 * 384 * 4);
  float* gi1f = (float*)alloc((size_t)32 * 4 * 384 * 4);
  float* gi1b = (float*)alloc((size_t)32 * 4 * 384 * 4);
  unsigned short* X  = (unsigned short*)alloc((size_t)2560 * 4 * 512 * 2);
  unsigned short* O  = (unsigned short*)alloc((size_t)2560 * 4 * 896 * 2);
  unsigned short* O2 = (unsigned short*)alloc((size_t)10240 * 512 * 2);
  float*          LG = (float*)alloc((size_t)10240 * 256 * 4);

  hipMemsetAsync(d_ws, 0, misc_bytes, stream);

  // encoder layer 0
  k_gi_enc<<<128, 384, 0, stream>>>(x, m0f_Wih, m0f_bih, gi0f, 80);
  k_gi_enc<<<128, 384, 0, stream>>>(x, m0b_Wih, m0b_bih, gi0b, 80);
  k_scan_enc<<<2, 512, 0, stream>>>(gi0f, gi0b, m0f_Whh, m0f_bhh, m0b_Whh, m0b_bhh, c0);
  // encoder layer 1
  k_gi_enc<<<128, 384, 0, stream>>>(c0, m1f_Wih, m1f_bih, gi1f, 256);
  k_gi_enc<<<128, 384, 0, stream>>>(c0, m1b_Wih, m1b_bih, gi1b, 256);
  k_scan_enc<<<2, 512, 0, stream>>>(gi1f, gi1b, m1f_Whh, m1f_bhh, m1b_Whh, m1b_bhh, c1);
  // wav input
  k_build_X<<<2560, 256, 0, stream>>>(y, E, c1, X);
  // recurrent wav GRU (cooperative, persistent)
  {
    void* args[] = { (void*)&w_Wih, (void*)&w_Whh, (void*)&w_bih, (void*)&w_bhh,
                     (void*)&X, (void*)&hbuf, (void*)&O, (void*)&flags, (void*)&gstep };
    hipLaunchCooperativeKernel((void*)k_wav_rnn, dim3(NG), dim3(256), args, 0, stream);
  }
  // head
  k_gemm<<<dim3(160, 8), 256, 0, stream>>>(O, Wp, bp, (void*)O2, 10240, 512, 896, 1, 1);
  k_gemm<<<dim3(160, 4), 256, 0, stream>>>(O2, Wd, bd, (void*)LG, 10240, 256, 512, 0, 0);
  k_nll<<<2560, 256, 0, stream>>>(LG, y, nacc);
  k_final<<<1, 1, 0, stream>>>(nacc, (float*)d_out);
}

// Round 2
// 12736.169 us; speedup vs baseline: 7.1479x; 7.1479x over previous
//
#include <hip/hip_runtime.h>
#include <stdint.h>
#include <math.h>

typedef __attribute__((ext_vector_type(8))) short bf16x8;
typedef __attribute__((ext_vector_type(4))) float f32x4;

#define BATCH 4
#define T_M 32
#define DE 128
#define T_W 2560
#define NG 224        /* wav-rnn workgroups; 896/224 = 4 units per WG */
#define RPW 12        /* gate rows per WG = 3 gates * 4 units */

__device__ __forceinline__ float b2f(unsigned short h) {
  return __uint_as_float(((unsigned int)h) << 16);
}
__device__ __forceinline__ unsigned short f2b(float f) {
  unsigned int u = __float_as_uint(f);
  u = u + 0x7fffu + ((u >> 16) & 1u);   // RNE
  return (unsigned short)(u >> 16);
}
__device__ __forceinline__ float blo(unsigned int u){ return __uint_as_float(u << 16); }
__device__ __forceinline__ float bhi(unsigned int u){ return __uint_as_float(u & 0xffff0000u); }
__device__ __forceinline__ float sigm(float x){ return 1.f / (1.f + __expf(-x)); }
__device__ __forceinline__ float gelu_exact(float x){ return 0.5f * x * (1.f + erff(x * 0.70710678118654752f)); }

// ---------------- fp32 -> bf16 cast ----------------
__global__ __launch_bounds__(256) void k_cast(const float* __restrict__ src,
                                              unsigned short* __restrict__ dst, int n)
{
  int i = blockIdx.x * 256 + threadIdx.x;
  if (i < n) dst[i] = f2b(src[i]);
}

// ---------------- encoder: input projections gi = in @ Wih^T + bih ----------------
__global__ __launch_bounds__(384) void k_gi_enc(
    const float* __restrict__ in, const float* __restrict__ Wih,
    const float* __restrict__ bih, float* __restrict__ out, int K)
{
  __shared__ float in_s[256];
  int tb = blockIdx.x;
  for (int i = threadIdx.x; i < K; i += 384) in_s[i] = in[tb * K + i];
  __syncthreads();
  int row = threadIdx.x;
  float acc = bih[row];
  const float* wr = Wih + row * K;
  for (int k = 0; k < K; ++k) acc += in_s[k] * wr[k];
  out[tb * 384 + row] = acc;
}

// ---------------- encoder: sequential scan, one WG per direction ----------------
__global__ __launch_bounds__(512) void k_scan_enc(
    const float* __restrict__ gi_f, const float* __restrict__ gi_b,
    const float* __restrict__ whh_f, const float* __restrict__ bhh_f,
    const float* __restrict__ whh_b, const float* __restrict__ bhh_b,
    float* __restrict__ c_out)   // (32,4,256)
{
  const int dir = blockIdx.x, tid = threadIdx.x;
  const float* gi  = dir ? gi_b  : gi_f;
  const float* whh = dir ? whh_b : whh_f;
  const float* bhh = dir ? bhh_b : bhh_f;
  __shared__ unsigned short h_s[BATCH][DE + 8];
  __shared__ float gh_s[384][4];
  __shared__ float bhh_s[384];
  for (int i = tid; i < 384; i += 512) bhh_s[i] = bhh[i];
  for (int i = tid; i < BATCH * (DE + 8); i += 512) ((unsigned short*)h_s)[i] = 0;
  __syncthreads();
  for (int s = 0; s < T_M; ++s) {
    int t = dir ? (T_M - 1 - s) : s;
    #pragma unroll
    for (int k3 = 0; k3 < 3; ++k3) {
      int d = tid + 512 * k3;
      int row = d >> 2, b = d & 3;
      const float* wr = whh + row * DE;
      float acc = 0.f;
      for (int j = 0; j < DE; j += 8) {
        float4 w0 = *(const float4*)(wr + j);
        float4 w1 = *(const float4*)(wr + j + 4);
        uint4  hv = *(const uint4*)&h_s[b][j];
        acc += w0.x * blo(hv.x) + w0.y * bhi(hv.x) + w0.z * blo(hv.y) + w0.w * bhi(hv.y);
        acc += w1.x * blo(hv.z) + w1.y * bhi(hv.z) + w1.z * blo(hv.w) + w1.w * bhi(hv.w);
      }
      gh_s[row][b] = acc + bhh_s[row];
    }
    __syncthreads();
    {
      int u = tid >> 2, b = tid & 3;
      const float* git = gi + (t * BATCH + b) * 384;
      float r = sigm(git[u] + gh_s[u][b]);
      float z = sigm(git[DE + u] + gh_s[DE + u][b]);
      float n = tanhf(git[2 * DE + u] + r * gh_s[2 * DE + u][b]);
      float hold = b2f(h_s[b][u]);
      float hnew = (1.f - z) * n + z * hold;
      c_out[(t * BATCH + b) * 256 + dir * DE + u] = hnew;
      h_s[b][u] = f2b(hnew);
    }
    __syncthreads();
  }
}

// ---------------- build wav-GRU input X = [embed, upsampled c] (bf16) ----------------
__global__ __launch_bounds__(256) void k_build_X(
    const float* __restrict__ y, const float* __restrict__ E,
    const float* __restrict__ c1, unsigned short* __restrict__ X)
{
  int t = blockIdx.x, c = threadIdx.x;
  int tm = t / 80;
  #pragma unroll
  for (int b = 0; b < BATCH; ++b) {
    float w = (t == 0) ? 0.f : y[(t - 1) * BATCH + b];
    int q = (int)floorf((w + 1.f) * 128.f);
    q = q < 0 ? 0 : (q > 255 ? 255 : q);
    unsigned short* xb = X + (size_t)(t * BATCH + b) * 512;
    xb[c]       = f2b(E[q * 256 + c]);
    xb[256 + c] = f2b(c1[(tm * BATCH + b) * 256 + c]);
  }
}

// ---------------- MFMA GEMM: C(MxN) = act(A(bf16 MxK) @ B(bf16 NxK)^T + bias) -------
// grid (M/128, N/128), block 256 (4 waves, 2x2 of 64x64)
__global__ __launch_bounds__(256) void k_mgemm(
    const unsigned short* __restrict__ A, const unsigned short* __restrict__ B,
    const float* __restrict__ bias, void* __restrict__ C,
    int M, int N, int K, int act, int c_bf16)
{
  __shared__ unsigned short As[128][40];
  __shared__ unsigned short Bs[128][40];
  const int tid = threadIdx.x;
  const int m0 = blockIdx.x * 128, n0 = blockIdx.y * 128;
  const int lane = tid & 63, wave = tid >> 6;
  const int wy = wave >> 1, wx = wave & 1;
  const int row16 = lane & 15, quad = lane >> 4;
  const int sr = tid >> 1, sc = (tid & 1) * 16;
  f32x4 acc[4][4] = {};
  for (int kt = 0; kt < K; kt += 32) {
    uint4 av  = *(const uint4*)(A + (size_t)(m0 + sr) * K + kt + sc);
    uint4 av2 = *(const uint4*)(A + (size_t)(m0 + sr) * K + kt + sc + 8);
    uint4 bv  = *(const uint4*)(B + (size_t)(n0 + sr) * K + kt + sc);
    uint4 bv2 = *(const uint4*)(B + (size_t)(n0 + sr) * K + kt + sc + 8);
    __syncthreads();
    *(uint4*)&As[sr][sc] = av; *(uint4*)&As[sr][sc + 8] = av2;
    *(uint4*)&Bs[sr][sc] = bv; *(uint4*)&Bs[sr][sc + 8] = bv2;
    __syncthreads();
    bf16x8 af[4], bf[4];
    #pragma unroll
    for (int i = 0; i < 4; ++i) af[i] = *(const bf16x8*)&As[wy * 64 + i * 16 + row16][quad * 8];
    #pragma unroll
    for (int j = 0; j < 4; ++j) bf[j] = *(const bf16x8*)&Bs[wx * 64 + j * 16 + row16][quad * 8];
    #pragma unroll
    for (int i = 0; i < 4; ++i)
      #pragma unroll
      for (int j = 0; j < 4; ++j)
        acc[i][j] = __builtin_amdgcn_mfma_f32_16x16x32_bf16(af[i], bf[j], acc[i][j], 0, 0, 0);
  }
  #pragma unroll
  for (int i = 0; i < 4; ++i) {
    #pragma unroll
    for (int j = 0; j < 4; ++j) {
      int col = n0 + wx * 64 + j * 16 + row16;
      float bs = bias[col];
      #pragma unroll
      for (int r = 0; r < 4; ++r) {
        int row = m0 + wy * 64 + i * 16 + quad * 4 + r;
        float v = acc[i][j][r] + bs;
        if (act) v = gelu_exact(v);
        if (c_bf16) ((unsigned short*)C)[(size_t)row * N + col] = f2b(v);
        else        ((float*)C)[(size_t)row * N + col] = v;
      }
    }
  }
}

// ---------------- wav GRU: persistent cooperative kernel ----------------
// All cross-WG data (h, flags, gstep) via relaxed AGENT atomics (sc1, LLC-coherent).
// NO threadfence -> no L2 writeback/invalidate. gi precomputed (incl. bih).
__global__ __launch_bounds__(256, 1) void k_wav_rnn(
    const float* __restrict__ whh,          // (2688,896) fp32
    const float* __restrict__ bhh,          // (2688,)
    const unsigned short* __restrict__ gi,  // (10240,2688) bf16 = X@Wih^T + bih
    unsigned int* __restrict__ hbuf32,      // (2,4,448) dwords of bf16 pairs, zeroed
    unsigned int* __restrict__ O32,         // (10240,448) dwords of bf16 pairs
    int* __restrict__ flags,                // NG*16 ints, zeroed
    int* __restrict__ gstep)                // zeroed
{
  const int wg = blockIdx.x, tid = threadIdx.x;
  const int lane = tid & 63, wave = tid >> 6;

  __shared__ unsigned short wcat_s[RPW][904];   // Whh rows (bf16), 904*2B stride (16B mult)
  __shared__ float phh_s[4][16][4];             // [wave][row][b]
  __shared__ unsigned int holdu[8];             // old h dwords [p*4+b]
  __shared__ float bhh_s[RPW];

  for (int idx = tid; idx < RPW * 896; idx += 256) {
    int r = idx / 896, c = idx - r * 896;
    int g = r >> 2, u = r & 3;
    wcat_s[r][c] = f2b(whh[(size_t)(g * 896 + wg * 4 + u) * 896 + c]);
  }
  if (tid < RPW) bhh_s[tid] = bhh[(tid >> 2) * 896 + wg * 4 + (tid & 3)];
  __syncthreads();

  const int row16 = lane & 15;
  const int mrow = row16 < RPW ? row16 : (RPW - 1);  // clamp dup (rows 12-15 unused)
  const int bcol = row16 & 3;
  const int quad = lane >> 4;

  for (int t = 0; t < T_W; ++t) {
    // --- load h(t) B-fragments straight from LLC (sc1 atomics) ---
    const unsigned long long* hq =
        (const unsigned long long*)hbuf32 + (size_t)(t & 1) * 896;
    unsigned long long bq0[7], bq1[7];
    #pragma unroll
    for (int kc = 0; kc < 7; ++kc) {
      int e0 = bcol * 896 + (wave * 7 + kc) * 32 + quad * 8;   // element index
      bq0[kc] = __hip_atomic_load(hq + (e0 >> 2),     __ATOMIC_RELAXED, __HIP_MEMORY_SCOPE_AGENT);
      bq1[kc] = __hip_atomic_load(hq + (e0 >> 2) + 1, __ATOMIC_RELAXED, __HIP_MEMORY_SCOPE_AGENT);
    }
    float gir = 0.f, giz = 0.f, gin = 0.f;
    if (wave == 0) {
      if (tid < 8) {
        int p = tid >> 2, b = tid & 3;
        holdu[p * 4 + b] = __hip_atomic_load(
            hbuf32 + (t & 1) * 1792 + b * 448 + wg * 2 + p,
            __ATOMIC_RELAXED, __HIP_MEMORY_SCOPE_AGENT);
      }
      if (tid < 16) {
        int u = tid >> 2, b = tid & 3;
        const unsigned short* g0 = gi + (size_t)(t * 4 + b) * 2688 + wg * 4 + u;
        gir = b2f(g0[0]); giz = b2f(g0[896]); gin = b2f(g0[1792]);
      }
    }

    // --- Whh . h via MFMA (28 chunks of K=32 across 4 waves) ---
    f32x4 ahh = {0.f, 0.f, 0.f, 0.f};
    #pragma unroll
    for (int kc = 0; kc < 7; ++kc) {
      bf16x8 a = *(const bf16x8*)&wcat_s[mrow][(wave * 7 + kc) * 32 + quad * 8];
      union { unsigned long long q[2]; bf16x8 v; } bb;
      bb.q[0] = bq0[kc]; bb.q[1] = bq1[kc];
      ahh = __builtin_amdgcn_mfma_f32_16x16x32_bf16(a, bb.v, ahh, 0, 0, 0);
    }
    if (row16 < 4) {
      #pragma unroll
      for (int r = 0; r < 4; ++r) phh_s[wave][quad * 4 + r][row16] = ahh[r];
    }
    __syncthreads();

    // --- finalize 16 h values in wave 0, publish via sc1 stores + flag ---
    if (wave == 0) {
      unsigned int hu = 0;
      if (tid < 16) {
        int u = tid >> 2, b = tid & 3;
        float ghr = phh_s[0][u][b] + phh_s[1][u][b] + phh_s[2][u][b] + phh_s[3][u][b] + bhh_s[u];
        float ghz = phh_s[0][4+u][b] + phh_s[1][4+u][b] + phh_s[2][4+u][b] + phh_s[3][4+u][b] + bhh_s[4+u];
        float ghn = phh_s[0][8+u][b] + phh_s[1][8+u][b] + phh_s[2][8+u][b] + phh_s[3][8+u][b] + bhh_s[8+u];
        float r = sigm(gir + ghr);
        float z = sigm(giz + ghz);
        float n = tanhf(gin + r * ghn);
        unsigned int hw = holdu[(u >> 1) * 4 + b];
        float hold = (u & 1) ? bhi(hw) : blo(hw);
        float hnew = (1.f - z) * n + z * hold;
        hu = f2b(hnew);
      }
      int p = tid >> 2, b = tid & 3;
      int s1 = (tid < 8) ? (8 * p + b)     : 0;
      int s2 = (tid < 8) ? (8 * p + 4 + b) : 0;
      unsigned int va = (unsigned int)__shfl((int)hu, s1, 64);
      unsigned int vb = (unsigned int)__shfl((int)hu, s2, 64);
      if (tid < 8) {
        unsigned int dw = (va & 0xffffu) | (vb << 16);
        __hip_atomic_store(hbuf32 + ((t + 1) & 1) * 1792 + b * 448 + wg * 2 + p, dw,
                           __ATOMIC_RELAXED, __HIP_MEMORY_SCOPE_AGENT);
        O32[(size_t)(t * 4 + b) * 448 + wg * 2 + p] = dw;
      }
      __builtin_amdgcn_s_waitcnt(0);        // h stores visible at LLC before flag
      asm volatile("" ::: "memory");
      if (tid == 0)
        __hip_atomic_store(flags + wg * 16, t + 1, __ATOMIC_RELAXED, __HIP_MEMORY_SCOPE_AGENT);
    }

    // --- global barrier: master gathers flags, publishes gstep ---
    if (wg == 0) {
      if (tid < NG) {
        while (__hip_atomic_load(flags + tid * 16, __ATOMIC_RELAXED, __HIP_MEMORY_SCOPE_AGENT) < t + 1) {}
      }
      __syncthreads();
      if (tid == 0)
        __hip_atomic_store(gstep, t + 1, __ATOMIC_RELAXED, __HIP_MEMORY_SCOPE_AGENT);
    } else {
      if (tid == 0) {
        while (__hip_atomic_load(gstep, __ATOMIC_RELAXED, __HIP_MEMORY_SCOPE_AGENT) < t + 1) {}
      }
      __syncthreads();
    }
    asm volatile("" ::: "memory");
  }
}

// ---------------- NLL ----------------
__global__ __launch_bounds__(256) void k_nll(
    const float* __restrict__ logits, const float* __restrict__ y,
    float* __restrict__ acc)
{
  int wid = threadIdx.x >> 6, lane = threadIdx.x & 63;
  int row = blockIdx.x * 4 + wid;
  const float* lr = logits + (size_t)row * 256;
  float v0 = lr[lane], v1 = lr[lane + 64], v2 = lr[lane + 128], v3 = lr[lane + 192];
  float mx = fmaxf(fmaxf(v0, v1), fmaxf(v2, v3));
  for (int off = 32; off > 0; off >>= 1) mx = fmaxf(mx, __shfl_xor(mx, off));
  float se = __expf(v0 - mx) + __expf(v1 - mx) + __expf(v2 - mx) + __expf(v3 - mx);
  for (int off = 32; off > 0; off >>= 1) se += __shfl_xor(se, off);
  if (lane == 0) {
    float w = y[row];
    int q = (int)floorf((w + 1.f) * 128.f);
    q = q < 0 ? 0 : (q > 255 ? 255 : q);
    float contrib = (logf(se) + mx) - lr[q];
    atomicAdd(acc, contrib);
  }
}

__global__ void k_final(const float* __restrict__ acc, float* __restrict__ out) {
  out[0] = acc[0] * (1.f / 10240.f);
}

// ---------------- host ----------------
extern "C" void kernel_launch(void* const* d_in, const int* in_sizes, int n_in,
                              void* d_out, int out_size, void* d_ws, size_t ws_size,
                              hipStream_t stream)
{
  const float* x       = (const float*)d_in[0];
  const float* y       = (const float*)d_in[1];
  const float* m0f_Wih = (const float*)d_in[2];
  const float* m0f_Whh = (const float*)d_in[3];
  const float* m0f_bih = (const float*)d_in[4];
  const float* m0f_bhh = (const float*)d_in[5];
  const float* m0b_Wih = (const float*)d_in[6];
  const float* m0b_Whh = (const float*)d_in[7];
  const float* m0b_bih = (const float*)d_in[8];
  const float* m0b_bhh = (const float*)d_in[9];
  const float* m1f_Wih = (const float*)d_in[10];
  const float* m1f_Whh = (const float*)d_in[11];
  const float* m1f_bih = (const float*)d_in[12];
  const float* m1f_bhh = (const float*)d_in[13];
  const float* m1b_Wih = (const float*)d_in[14];
  const float* m1b_Whh = (const float*)d_in[15];
  const float* m1b_bih = (const float*)d_in[16];
  const float* m1b_bhh = (const float*)d_in[17];
  const float* w_Wih   = (const float*)d_in[18];
  const float* w_Whh   = (const float*)d_in[19];
  const float* w_bih   = (const float*)d_in[20];
  const float* w_bhh   = (const float*)d_in[21];
  const float* Wp      = (const float*)d_in[22];
  const float* bp      = (const float*)d_in[23];
  const float* E       = (const float*)d_in[24];
  const float* Wd      = (const float*)d_in[25];
  const float* bd      = (const float*)d_in[26];

  char* ws = (char*)d_ws;
  size_t off = 0;
  auto alloc = [&](size_t bytes) -> void* {
    void* p = ws + off;
    off += (bytes + 255) & ~(size_t)255;
    return p;
  };
  // misc (zeroed each launch)
  int*          flags = (int*)alloc(NG * 16 * sizeof(int));
  int*          gstep = (int*)alloc(64);
  float*        nacc  = (float*)alloc(64);
  unsigned int* hbuf  = (unsigned int*)alloc(2 * 1792 * sizeof(unsigned int));
  size_t misc_bytes = off;

  float* c0   = (float*)alloc((size_t)32 * 4 * 256 * 4);
  float* c1   = (float*)alloc((size_t)32 * 4 * 256 * 4);
  float* gi0f = (float*)alloc((size_t)32 * 4 * 384 * 4);
  float* gi0b = (float*)alloc((size_t)32 * 4 * 384 * 4);
  float* gi1f = (float*)alloc((size_t)32 * 4 * 384 * 4);
  float* gi1b = (float*)alloc((size_t)32 * 4 * 384 * 4);
  unsigned short* X     = (unsigned short*)alloc((size_t)10240 * 512 * 2);
  unsigned short* gi_w  = (unsigned short*)alloc((size_t)10240 * 2688 * 2);
  unsigned int*   O32   = (unsigned int*)alloc((size_t)10240 * 448 * 4);
  unsigned short* O2    = (unsigned short*)alloc((size_t)10240 * 512 * 2);
  float*          LG    = (float*)alloc((size_t)10240 * 256 * 4);
  unsigned short* Wih_b = (unsigned short*)alloc((size_t)2688 * 512 * 2);
  unsigned short* Wp_b  = (unsigned short*)alloc((size_t)512 * 896 * 2);
  unsigned short* Wd_b  = (unsigned short*)alloc((size_t)256 * 512 * 2);

  hipMemsetAsync(d_ws, 0, misc_bytes, stream);

  // weight casts
  k_cast<<<(2688 * 512 + 255) / 256, 256, 0, stream>>>(w_Wih, Wih_b, 2688 * 512);
  k_cast<<<(512 * 896 + 255) / 256, 256, 0, stream>>>(Wp, Wp_b, 512 * 896);
  k_cast<<<(256 * 512 + 255) / 256, 256, 0, stream>>>(Wd, Wd_b, 256 * 512);

  // encoder
  k_gi_enc<<<128, 384, 0, stream>>>(x, m0f_Wih, m0f_bih, gi0f, 80);
  k_gi_enc<<<128, 384, 0, stream>>>(x, m0b_Wih, m0b_bih, gi0b, 80);
  k_scan_enc<<<2, 512, 0, stream>>>(gi0f, gi0b, m0f_Whh, m0f_bhh, m0b_Whh, m0b_bhh, c0);
  k_gi_enc<<<128, 384, 0, stream>>>(c0, m1f_Wih, m1f_bih, gi1f, 256);
  k_gi_enc<<<128, 384, 0, stream>>>(c0, m1b_Wih, m1b_bih, gi1b, 256);
  k_scan_enc<<<2, 512, 0, stream>>>(gi1f, gi1b, m1f_Whh, m1f_bhh, m1b_Whh, m1b_bhh, c1);

  // wav input + precomputed input projection (includes bih)
  k_build_X<<<2560, 256, 0, stream>>>(y, E, c1, X);
  k_mgemm<<<dim3(80, 21), 256, 0, stream>>>(X, Wih_b, w_bih, (void*)gi_w,
                                            10240, 2688, 512, 0, 1);

  // recurrent wav GRU (cooperative, persistent)
  {
    void* args[] = { (void*)&w_Whh, (void*)&w_bhh, (void*)&gi_w, (void*)&hbuf,
                     (void*)&O32, (void*)&flags, (void*)&gstep };
    hipLaunchCooperativeKernel((void*)k_wav_rnn, dim3(NG), dim3(256), args, 0, stream);
  }

  // head
  k_mgemm<<<dim3(80, 4), 256, 0, stream>>>((const unsigned short*)O32, Wp_b, bp,
                                           (void*)O2, 10240, 512, 896, 1, 1);
  k_mgemm<<<dim3(80, 2), 256, 0, stream>>>(O2, Wd_b, bd, (void*)LG,
                                           10240, 256, 512, 0, 0);
  k_nll<<<2560, 256, 0, stream>>>(LG, y, nacc);
  k_final<<<1, 1, 0, stream>>>(nacc, (float*)d_out);
}